// Round 7
// baseline (97.527 us; speedup 1.0000x reference)
//
#include <hip/hip_runtime.h>
#include <hip/hip_bf16.h>

#define BB 4
#define CC 256
#define HH 64
#define WW 64
#define OO 256
#define NK2 9
#define HWP (HH*WW)      // 4096
#define KD (NK2*CC)      // 2304
#define PART_ELEMS (BB*OO*HWP)        // 4,194,304
#define XT_BYTES   8388608ull
#define WT_BYTES   1179648ull
#define PART_OFF   (XT_BYTES + WT_BYTES)

typedef __bf16 bf16x8 __attribute__((ext_vector_type(8)));
typedef float f32x4 __attribute__((ext_vector_type(4)));
typedef float f32x8 __attribute__((ext_vector_type(8)));
typedef unsigned short u16x8 __attribute__((ext_vector_type(8)));

static __device__ __forceinline__ float bf2f(unsigned short v) {
  return __uint_as_float(((unsigned)v) << 16);
}
static __device__ __forceinline__ unsigned short f2bf(float f) {
  __hip_bfloat16 h = __float2bfloat16(f);
  return __builtin_bit_cast(unsigned short, h);
}

// x [B][C][H][W] fp32  ->  xt [B][H][W][C] bf16
__global__ void k_xpose(const float* __restrict__ x, unsigned short* __restrict__ xt) {
  __shared__ float tile[32][33];
  int b  = blockIdx.z;
  int c0 = blockIdx.y * 32;
  int p0 = blockIdx.x * 32;
  int tx = threadIdx.x & 31;
  int ty = threadIdx.x >> 5;
  const float* src = x + ((size_t)b * CC + c0) * HWP + p0;
#pragma unroll
  for (int i = 0; i < 4; ++i)
    tile[ty + i * 8][tx] = src[(size_t)(ty + i * 8) * HWP + tx];
  __syncthreads();
  unsigned short* dst = xt + ((size_t)b * HWP + p0) * CC + c0;
#pragma unroll
  for (int i = 0; i < 4; ++i) {
    float v = tile[tx][ty + i * 8];
    dst[(size_t)(ty + i * 8) * CC + tx] = f2bf(v);
  }
}

// weight [O][C][3][3] fp32 -> wt [O][kpt][C] bf16
__global__ void k_wt(const float* __restrict__ w, unsigned short* __restrict__ wt) {
  int i = blockIdx.x * 256 + threadIdx.x;
  if (i >= OO * KD) return;
  int o = i / KD;
  int r = i - o * KD;
  int kpt = r >> 8;
  int c = r & 255;
  wt[i] = f2bf(w[((size_t)o * CC + c) * NK2 + kpt]);
}

// Staged-x implicit GEMM.
// Block: 256 thr / 4 waves; Mt=128 (2 image rows), NSLICE c-slices of 32ch
// processed sequentially with acc carried (K-extension). Each slice:
// stage 14 rows x 64px x 32ch (56KB) in LDS, then 9 kpt iterations of
// {bilinear panel build from LDS (global fallback if |offY| out of window)
//  -> MFMA K=32}. LDS: stage 56KB + panel 8KB = 64KB -> 2 blocks/CU.
// LDS layouts are chunk-plane (conflict-free): stage[row][c4][64px][16B],
// panel[c4][128px][16B].
template<int NSLICE, int BF16OUT>
__launch_bounds__(256, 2)
__global__ void k_dcn_s(const unsigned short* __restrict__ xt,
                        const unsigned short* __restrict__ wt,
                        const float* __restrict__ sp,
                        void* __restrict__ dstv) {
  __shared__ __align__(16) unsigned char S[65536];
  unsigned char* P = S + 57344;            // panel: 4 x 2048B planes

  const int tid = threadIdx.x;
  constexpr int CGN = 8 / NSLICE;          // # c-groups (blocks per tile)
  constexpr int NBLK = 128 * CGN;
  const int bid = blockIdx.x;
  const int swz = (bid & 7) * (NBLK / 8) + (bid >> 3);   // XCD-chunked
  const int tile = swz / CGN;
  const int cg = swz % CGN;
  const int y0 = (tile & 31) * 2;
  const int b = tile >> 5;

  // panel-build mapping: 2 threads per pixel, 16ch (2 chunks) each
  const int pm = tid >> 1;                 // panel row 0..127
  const int t2 = tid & 1;
  const int yim = y0 + (pm >> 6);
  const int xim = pm & 63;

  // staging mapping: 4 threads per pixel, 8ch (1 chunk) each
  const int spx = tid >> 2;                // 0..63
  const int sc4 = tid & 3;                 // chunk
  const unsigned sdst = (unsigned)(sc4 * 1024 + spx * 16);

  // gemm mapping: 4 waves, wave tile o64 x m128
  const int wv = tid >> 6;
  const int lane = tid & 63;
  const int l15 = lane & 15;
  const int lg = lane >> 4;

  // prefetch all per-kpt offsets for this pixel (static indexing)
  float offY[NK2], offX[NK2];
#pragma unroll
  for (int t = 0; t < NK2; ++t) {
    offY[t] = sp[((size_t)b * 18 + 2 * t) * HWP + yim * WW + xim];
    offX[t] = sp[((size_t)b * 18 + 2 * t + 1) * HWP + yim * WW + xim];
  }

  f32x4 acc[4][8];
#pragma unroll
  for (int i = 0; i < 4; ++i)
#pragma unroll
    for (int j = 0; j < 8; ++j)
      acc[i][j] = (f32x4){0.f, 0.f, 0.f, 0.f};

  const unsigned short* xb = xt + (size_t)b * HWP * CC;

#pragma unroll
  for (int s = 0; s < NSLICE; ++s) {
    const int cs = cg * NSLICE + s;
    // ---- stage 14 rows [y0-6, y0+7] of this c-slice ----
    {
      const unsigned short* xsrc = xb + cs * 32 + sc4 * 8;
#pragma unroll
      for (int half = 0; half < 2; ++half) {
        u16x8 ld[7];
#pragma unroll
        for (int r = 0; r < 7; ++r) {
          int gy = y0 - 6 + half * 7 + r;
          gy = min(max(gy, 0), HH - 1);
          ld[r] = *reinterpret_cast<const u16x8*>(xsrc + ((size_t)gy * WW + spx) * CC);
        }
#pragma unroll
        for (int r = 0; r < 7; ++r)
          *reinterpret_cast<u16x8*>(S + (half * 7 + r) * 4096 + sdst) = ld[r];
      }
    }
    __syncthreads();

#pragma unroll
    for (int kpt = 0; kpt < NK2; ++kpt) {
      // ---- build panel for (cs, kpt) ----
      {
        float py = (float)yim + offY[kpt];
        float px = (float)xim + offX[kpt];
        float fy = floorf(py), fx = floorf(px);
        float ly = py - fy, lx = px - fx;
        int y0i = (int)fy, x0i = (int)fx;
        int y1i = y0i + 1, x1i = x0i + 1;
        bool vy0 = (y0i >= 0) & (y0i < HH);
        bool vy1 = (y1i >= 0) & (y1i < HH);
        bool vx0 = (x0i >= 0) & (x0i < WW);
        bool vx1 = (x1i >= 0) & (x1i < WW);
        float w00 = (1.f - ly) * (1.f - lx);
        float w01 = (1.f - ly) * lx;
        float w10 = ly * (1.f - lx);
        float w11 = ly * lx;
        w00 = (vy0 && vx0) ? w00 : 0.f;
        w01 = (vy0 && vx1) ? w01 : 0.f;
        w10 = (vy1 && vx0) ? w10 : 0.f;
        w11 = (vy1 && vx1) ? w11 : 0.f;
        int xc0 = min(max(x0i, 0), WW - 1), xc1 = min(max(x1i, 0), WW - 1);
        bool inwin = (py >= (float)(y0 - 6)) && (py <= (float)(y0 + 7));
        int s0 = min(max(y0i - (y0 - 6), 0), 13);
        int s1 = min(s0 + 1, 13);
        int yc0 = min(max(y0i, 0), HH - 1), yc1 = min(max(y1i, 0), HH - 1);
#pragma unroll
        for (int ch = 0; ch < 2; ++ch) {
          const int c4 = t2 * 2 + ch;              // chunk index 0..3
          u16x8 a00, a01, a10, a11;
          if (__builtin_expect(inwin, 1)) {
            a00 = *reinterpret_cast<const u16x8*>(S + s0 * 4096 + c4 * 1024 + xc0 * 16);
            a01 = *reinterpret_cast<const u16x8*>(S + s0 * 4096 + c4 * 1024 + xc1 * 16);
            a10 = *reinterpret_cast<const u16x8*>(S + s1 * 4096 + c4 * 1024 + xc0 * 16);
            a11 = *reinterpret_cast<const u16x8*>(S + s1 * 4096 + c4 * 1024 + xc1 * 16);
          } else {
            const unsigned short* q = xb + cs * 32 + c4 * 8;
            a00 = *reinterpret_cast<const u16x8*>(q + ((size_t)yc0 * WW + xc0) * CC);
            a01 = *reinterpret_cast<const u16x8*>(q + ((size_t)yc0 * WW + xc1) * CC);
            a10 = *reinterpret_cast<const u16x8*>(q + ((size_t)yc1 * WW + xc0) * CC);
            a11 = *reinterpret_cast<const u16x8*>(q + ((size_t)yc1 * WW + xc1) * CC);
          }
          u16x8 r;
#pragma unroll
          for (int j = 0; j < 8; ++j) {
            float v = fmaf(w11, bf2f(a11[j]),
                      fmaf(w10, bf2f(a10[j]),
                      fmaf(w01, bf2f(a01[j]), w00 * bf2f(a00[j]))));
            r[j] = f2bf(v);
          }
          *reinterpret_cast<u16x8*>(P + c4 * 2048 + pm * 16) = r;
        }
      }
      __syncthreads();

      // ---- MFMA: K = 32 (one chunk-set), 4x8 fragments per wave ----
      {
        bf16x8 afr[4], bfr[8];
#pragma unroll
        for (int fm = 0; fm < 4; ++fm)
          afr[fm] = __builtin_bit_cast(bf16x8, *reinterpret_cast<const u16x8*>(
              wt + (size_t)(wv * 64 + fm * 16 + l15) * KD + kpt * CC + cs * 32 + lg * 8));
#pragma unroll
        for (int fn = 0; fn < 8; ++fn)
          bfr[fn] = __builtin_bit_cast(bf16x8, *reinterpret_cast<const u16x8*>(
              P + lg * 2048 + (fn * 16 + l15) * 16));
#pragma unroll
        for (int fm = 0; fm < 4; ++fm)
#pragma unroll
          for (int fn = 0; fn < 8; ++fn)
            acc[fm][fn] = __builtin_amdgcn_mfma_f32_16x16x32_bf16(afr[fm], bfr[fn], acc[fm][fn], 0, 0, 0);
      }
      __syncthreads();
    }
  }

  // ---- epilogue: C/D col=l15 -> m, row=4*lg+r -> o ----
#pragma unroll
  for (int fm = 0; fm < 4; ++fm) {
#pragma unroll
    for (int fn = 0; fn < 8; ++fn) {
#pragma unroll
      for (int r = 0; r < 4; ++r) {
        int o = wv * 64 + fm * 16 + lg * 4 + r;
        int m = fn * 16 + l15;
        size_t idx = (((size_t)b * OO + o) * HH + y0 + (m >> 6)) * WW + (m & 63);
        float v = acc[fm][fn][r];
        if (BF16OUT) {
          ((unsigned short*)dstv)[(size_t)cg * PART_ELEMS + idx] = f2bf(v);
        } else {
          ((float*)dstv)[idx] = fmaxf(v, 0.0f);
        }
      }
    }
  }
}

// out = relu(p0+p1+p2+p3) from bf16 parts
__global__ void k_reduce4(const unsigned short* __restrict__ parts, float* __restrict__ out, int n8) {
  int i = blockIdx.x * 256 + threadIdx.x;
  if (i >= n8) return;
  const u16x8* p = (const u16x8*)parts;
  u16x8 a = p[i];
  u16x8 b = p[i + PART_ELEMS / 8];
  u16x8 c = p[i + 2 * (PART_ELEMS / 8)];
  u16x8 d = p[i + 3 * (PART_ELEMS / 8)];
  f32x8 o;
#pragma unroll
  for (int j = 0; j < 8; ++j)
    o[j] = fmaxf(bf2f(a[j]) + bf2f(b[j]) + bf2f(c[j]) + bf2f(d[j]), 0.0f);
  *reinterpret_cast<f32x8*>(out + (size_t)i * 8) = o;
}

extern "C" void kernel_launch(void* const* d_in, const int* in_sizes, int n_in,
                              void* d_out, int out_size, void* d_ws, size_t ws_size,
                              hipStream_t stream) {
  const float* x = (const float*)d_in[0];
  const float* sp = (const float*)d_in[1];
  const float* w = (const float*)d_in[2];
  float* out = (float*)d_out;

  unsigned short* xt = (unsigned short*)d_ws;
  unsigned short* wt = (unsigned short*)((char*)d_ws + XT_BYTES);
  unsigned short* parts = (unsigned short*)((char*)d_ws + PART_OFF);

  k_xpose<<<dim3(HWP / 32, CC / 32, BB), 256, 0, stream>>>(x, xt);
  k_wt<<<(OO * KD + 255) / 256, 256, 0, stream>>>(w, wt);

  const size_t need = PART_OFF + 4ull * PART_ELEMS * sizeof(unsigned short);
  if (ws_size >= need) {
    k_dcn_s<2, 1><<<512, 256, 0, stream>>>(xt, wt, sp, parts);
    k_reduce4<<<PART_ELEMS / 8 / 256, 256, 0, stream>>>(parts, out, PART_ELEMS / 8);
  } else {
    k_dcn_s<8, 0><<<128, 256, 0, stream>>>(xt, wt, sp, out);
  }
}

// Round 8
// 60.318 us; speedup vs baseline: 1.6169x; 1.6169x over previous
//
#include <hip/hip_runtime.h>
#include <hip/hip_bf16.h>

#define BB 4
#define CC 256
#define HH 64
#define WW 64
#define OO 256
#define NK2 9
#define HWP (HH*WW)      // 4096
#define KD (NK2*CC)      // 2304
#define PART_ELEMS (BB*OO*HWP)        // 4,194,304
#define XT_BYTES   8388608ull
#define WT_BYTES   1179648ull
#define PART_OFF   (XT_BYTES + WT_BYTES)

typedef __bf16 bf16x8 __attribute__((ext_vector_type(8)));
typedef float f32x4 __attribute__((ext_vector_type(4)));
typedef float f32x8 __attribute__((ext_vector_type(8)));
typedef unsigned short u16x8 __attribute__((ext_vector_type(8)));

static __device__ __forceinline__ float bf2f(unsigned short v) {
  return __uint_as_float(((unsigned)v) << 16);
}
static __device__ __forceinline__ unsigned short f2bf(float f) {
  __hip_bfloat16 h = __float2bfloat16(f);
  return __builtin_bit_cast(unsigned short, h);
}

// x [B][C][H][W] fp32  ->  xt [B][H][W][C] bf16
__global__ void k_xpose(const float* __restrict__ x, unsigned short* __restrict__ xt) {
  __shared__ float tile[32][33];
  int b  = blockIdx.z;
  int c0 = blockIdx.y * 32;
  int p0 = blockIdx.x * 32;
  int tx = threadIdx.x & 31;
  int ty = threadIdx.x >> 5;
  const float* src = x + ((size_t)b * CC + c0) * HWP + p0;
#pragma unroll
  for (int i = 0; i < 4; ++i)
    tile[ty + i * 8][tx] = src[(size_t)(ty + i * 8) * HWP + tx];
  __syncthreads();
  unsigned short* dst = xt + ((size_t)b * HWP + p0) * CC + c0;
#pragma unroll
  for (int i = 0; i < 4; ++i) {
    float v = tile[tx][ty + i * 8];
    dst[(size_t)(ty + i * 8) * CC + tx] = f2bf(v);
  }
}

// weight [O][C][3][3] fp32 -> wt2 [kpt][kk][o][32ch-frag] bf16
// (one MFMA A-fragment instruction reads 16 o-rows x 64B = 1KB contiguous)
__global__ void k_wt(const float* __restrict__ w, unsigned short* __restrict__ wt) {
  int i = blockIdx.x * 256 + threadIdx.x;
  if (i >= OO * KD) return;
  int kpt = i >> 16;              // /65536  (8*256*32)
  int rem = i & 65535;
  int kk = rem >> 13;             // /8192   (256*32)
  int rem2 = rem & 8191;
  int o = rem2 >> 5;
  int f = rem2 & 31;              // lg*8+j
  int c = kk * 32 + f;
  wt[i] = f2bf(w[((size_t)o * CC + c) * NK2 + kpt]);
}

// Implicit GEMM, Mt=128 (2 image rows), Nt=256, 512 threads / 8 waves.
// Wave tile: o32 x m128. Gathers: 8 lanes cover 128B contiguous per pixel.
// Weights: packed layout -> each fragment load instruction is 1KB contiguous.
template<int KPTN, int NG, int BF16OUT>
__launch_bounds__(512)
__global__ void k_dcn(const unsigned short* __restrict__ xt,
                      const unsigned short* __restrict__ wt,
                      const float* __restrict__ sp,
                      void* __restrict__ dstv) {
  __shared__ __align__(16) unsigned short Alds[128 * 256];   // 64 KB

  const int tid = threadIdx.x;
  constexpr int NBLK = NG * BB * (HH / 2);
  const int hw = blockIdx.x;
  const int swz = (hw & 7) * (NBLK / 8) + (hw >> 3);
  const int g = swz % NG;                   // kpt group
  const int rest = swz / NG;
  const int y0 = (rest & 31) * 2;
  const int b = rest >> 5;
  const int kpt0 = g * KPTN;

  // sampling mapping: 8 threads per pixel (128B granule), 2 row-halves
  const int t8 = tid & 7;                   // 16B chunk within 128B granule
  const int pxb = tid >> 3;                 // pixel x 0..63; row = y0 + half

  // mfma mapping: 8 waves x (o32 x m128)
  const int wv = tid >> 6;                  // 0..7
  const int lane = tid & 63;
  const int l15 = lane & 15;
  const int lg = lane >> 4;
  const int obase = wv * 32;

  // prefetch per-kpt offsets for both row-halves (static indexing)
  float offY[2][KPTN], offX[2][KPTN];
#pragma unroll
  for (int h = 0; h < 2; ++h)
#pragma unroll
    for (int t = 0; t < KPTN; ++t) {
      offY[h][t] = sp[((size_t)b * 18 + 2 * (kpt0 + t)) * HWP + (y0 + h) * WW + pxb];
      offX[h][t] = sp[((size_t)b * 18 + 2 * (kpt0 + t) + 1) * HWP + (y0 + h) * WW + pxb];
    }

  f32x4 acc[2][8];
#pragma unroll
  for (int i = 0; i < 2; ++i)
#pragma unroll
    for (int j = 0; j < 8; ++j)
      acc[i][j] = (f32x4){0.f, 0.f, 0.f, 0.f};

  // weight fragment base (packed layout): + (kpt*8+kk)*8192 in the loop
  const unsigned short* wbase[2];
#pragma unroll
  for (int fm = 0; fm < 2; ++fm)
    wbase[fm] = wt + (size_t)(obase + fm * 16 + l15) * 32 + lg * 8;

  char* Ab = (char*)Alds;
  const unsigned short* xb = xt + (size_t)b * HWP * CC;

#pragma unroll
  for (int t = 0; t < KPTN; ++t) {
    const int kpt = kpt0 + t;
    // ---- build sampled panel [128 m][256 c] in LDS ----
#pragma unroll
    for (int h = 0; h < 2; ++h) {
      const int pm = h * 64 + pxb;
      float py = (float)(y0 + h) + offY[h][t];
      float pxx = (float)pxb + offX[h][t];
      float fy = floorf(py), fx = floorf(pxx);
      float ly = py - fy, lx = pxx - fx;
      int y0i = (int)fy, x0i = (int)fx;
      int y1i = y0i + 1, x1i = x0i + 1;
      bool vy0 = (y0i >= 0) & (y0i < HH);
      bool vy1 = (y1i >= 0) & (y1i < HH);
      bool vx0 = (x0i >= 0) & (x0i < WW);
      bool vx1 = (x1i >= 0) & (x1i < WW);
      float w00 = (1.f - ly) * (1.f - lx);
      float w01 = (1.f - ly) * lx;
      float w10 = ly * (1.f - lx);
      float w11 = ly * lx;
      w00 = (vy0 && vx0) ? w00 : 0.f;
      w01 = (vy0 && vx1) ? w01 : 0.f;
      w10 = (vy1 && vx0) ? w10 : 0.f;
      w11 = (vy1 && vx1) ? w11 : 0.f;
      int yc0 = min(max(y0i, 0), HH - 1), yc1 = min(max(y1i, 0), HH - 1);
      int xc0 = min(max(x0i, 0), WW - 1), xc1 = min(max(x1i, 0), WW - 1);
      const unsigned short* p00 = xb + (yc0 * WW + xc0) * CC + t8 * 8;
      const unsigned short* p01 = xb + (yc0 * WW + xc1) * CC + t8 * 8;
      const unsigned short* p10 = xb + (yc1 * WW + xc0) * CC + t8 * 8;
      const unsigned short* p11 = xb + (yc1 * WW + xc1) * CC + t8 * 8;
#pragma unroll
      for (int cg = 0; cg < 4; ++cg) {
        // 8 lanes of one pixel read 128B contiguous per instruction
        u16x8 a00 = *reinterpret_cast<const u16x8*>(p00 + cg * 64);
        u16x8 a01 = *reinterpret_cast<const u16x8*>(p01 + cg * 64);
        u16x8 a10 = *reinterpret_cast<const u16x8*>(p10 + cg * 64);
        u16x8 a11 = *reinterpret_cast<const u16x8*>(p11 + cg * 64);
        u16x8 r;
#pragma unroll
        for (int j = 0; j < 8; ++j) {
          float s = fmaf(w11, bf2f(a11[j]),
                    fmaf(w10, bf2f(a10[j]),
                    fmaf(w01, bf2f(a01[j]), w00 * bf2f(a00[j]))));
          r[j] = f2bf(s);
        }
        unsigned bo = (unsigned)(pm * 512 + cg * 128 + t8 * 16) ^ (unsigned)((pm & 7) << 4);
        *reinterpret_cast<u16x8*>(Ab + bo) = r;
      }
    }
    __syncthreads();

    // ---- MFMA: K = 256 channels, 8 chunks of 32, reg-double-buffered ----
#define LOADK(AF, BF, KK)                                                          \
    {                                                                              \
      _Pragma("unroll")                                                            \
      for (int fm = 0; fm < 2; ++fm)                                               \
        AF[fm] = __builtin_bit_cast(bf16x8,                                        \
            *reinterpret_cast<const u16x8*>(wbase[fm] + (size_t)(kpt * 8 + (KK)) * 8192)); \
      _Pragma("unroll")                                                            \
      for (int fn = 0; fn < 8; ++fn) {                                             \
        int mr = fn * 16 + l15;                                                    \
        unsigned bo = (unsigned)(mr * 512 + (KK) * 64 + lg * 16) ^ (unsigned)((mr & 7) << 4); \
        BF[fn] = __builtin_bit_cast(bf16x8, *reinterpret_cast<const u16x8*>(Ab + bo)); \
      }                                                                            \
    }
#define DOMFMA(AF, BF)                                                             \
    {                                                                              \
      _Pragma("unroll")                                                            \
      for (int fm = 0; fm < 2; ++fm)                                               \
        _Pragma("unroll")                                                          \
        for (int fn = 0; fn < 8; ++fn)                                             \
          acc[fm][fn] = __builtin_amdgcn_mfma_f32_16x16x32_bf16(AF[fm], BF[fn], acc[fm][fn], 0, 0, 0); \
    }
    {
      bf16x8 a0[2], a1[2];
      bf16x8 b0[8], b1[8];
      LOADK(a0, b0, 0);
#pragma unroll
      for (int kk = 0; kk < 8; ++kk) {
        if ((kk & 1) == 0) {
          if (kk < 7) LOADK(a1, b1, kk + 1);
          DOMFMA(a0, b0);
        } else {
          if (kk < 7) LOADK(a0, b0, kk + 1);
          DOMFMA(a1, b1);
        }
      }
    }
    __syncthreads();
  }

  // ---- epilogue: C/D col=l15 -> m, row=4*lg+r -> o ----
#pragma unroll
  for (int fm = 0; fm < 2; ++fm) {
#pragma unroll
    for (int fn = 0; fn < 8; ++fn) {
#pragma unroll
      for (int r = 0; r < 4; ++r) {
        int o = obase + fm * 16 + lg * 4 + r;
        int m = fn * 16 + l15;
        int yy = y0 + (m >> 6);
        int xx = m & 63;
        size_t idx = (((size_t)b * OO + o) * HH + yy) * WW + xx;
        float v = acc[fm][fn][r];
        if (BF16OUT) {
          ((unsigned short*)dstv)[(size_t)g * PART_ELEMS + idx] = f2bf(v);
        } else {
          ((float*)dstv)[idx] = fmaxf(v, 0.0f);
        }
      }
    }
  }
}

// out = relu(p0+p1+p2) from bf16 parts, 8 elems/thread
__global__ void k_reduce(const unsigned short* __restrict__ parts, float* __restrict__ out, int n8) {
  int i = blockIdx.x * 256 + threadIdx.x;
  if (i >= n8) return;
  const u16x8* p0 = (const u16x8*)parts;
  const u16x8* p1 = p0 + (PART_ELEMS / 8);
  const u16x8* p2 = p1 + (PART_ELEMS / 8);
  u16x8 a = p0[i], b = p1[i], c = p2[i];
  f32x8 o;
#pragma unroll
  for (int j = 0; j < 8; ++j)
    o[j] = fmaxf(bf2f(a[j]) + bf2f(b[j]) + bf2f(c[j]), 0.0f);
  *reinterpret_cast<f32x8*>(out + (size_t)i * 8) = o;
}

extern "C" void kernel_launch(void* const* d_in, const int* in_sizes, int n_in,
                              void* d_out, int out_size, void* d_ws, size_t ws_size,
                              hipStream_t stream) {
  const float* x = (const float*)d_in[0];
  const float* sp = (const float*)d_in[1];
  const float* w = (const float*)d_in[2];
  float* out = (float*)d_out;

  unsigned short* xt = (unsigned short*)d_ws;
  unsigned short* wt = (unsigned short*)((char*)d_ws + XT_BYTES);
  unsigned short* parts = (unsigned short*)((char*)d_ws + PART_OFF);

  k_xpose<<<dim3(HWP / 32, CC / 32, BB), 256, 0, stream>>>(x, xt);
  k_wt<<<(OO * KD + 255) / 256, 256, 0, stream>>>(w, wt);

  const size_t need = PART_OFF + 3ull * PART_ELEMS * sizeof(unsigned short);
  if (ws_size >= need) {
    k_dcn<3, 3, 1><<<3 * BB * (HH / 2), 512, 0, stream>>>(xt, wt, sp, parts);
    k_reduce<<<PART_ELEMS / 8 / 256, 256, 0, stream>>>(parts, out, PART_ELEMS / 8);
  } else {
    k_dcn<9, 1, 0><<<BB * (HH / 2), 512, 0, stream>>>(xt, wt, sp, out);
  }
}